// Round 11
// baseline (204.424 us; speedup 1.0000x reference)
//
#include <hip/hip_runtime.h>
#include <stdint.h>

// Fused MLP decode, MFMA f16. Wave = 64 points (4 sub-tiles of 16), 4-wave wg.
// Weights in workgroup LDS (fragment-order, conflict-free b128). Feature
// fragments generated in MFMA A-layout via one Chebyshev chain. Hidden-layer
// silu via LDS LUT (1024-entry linear-interp sigma over u=-log2e*x) — no
// transcendentals in the hot loop except 2 sincos + 1 final sigmoid.
// Scale-folding: W0,b0 pre-scaled by c=-log2e so MFMA yields u directly;
// p=u*sigma fed to L1 (c cancels: W1 unscaled, b1 scaled by c); Wout scaled
// by -ln2. ZERO barriers in the loop (wave-private H, in-order DS pipe).
// NOTE: __launch_bounds__ has NO min-waves arg (",4" caused 64-VGPR spills).

typedef _Float16 half8  __attribute__((ext_vector_type(8)));
typedef _Float16 half4v __attribute__((ext_vector_type(4)));
typedef _Float16 half2v __attribute__((ext_vector_type(2)));
typedef float f32x4 __attribute__((ext_vector_type(4)));

#define LOG2E 1.44269504088896340736f
#define NLN2  -0.6931471805599453f         // -ln2 = 1/(-log2e)
#define CSCL  -1.44269504088896340736f     // c = -log2e
#define BASE_LOGIT -0.84729786038720367f   // log(0.3/0.7)
#define CSANMAX 28700.0f
#define IC_VAL 8610.0f                     // 0.3 * 28700

__device__ __forceinline__ float fast_exp2(float x) { return __builtin_amdgcn_exp2f(x); }
__device__ __forceinline__ float fast_rcp(float x)  { return __builtin_amdgcn_rcpf(x); }
__device__ __forceinline__ float sigf(float x)  { return fast_rcp(1.0f + fast_exp2(-LOG2E * x)); }
__device__ __forceinline__ half2v pkh(float a, float b) {
  return __builtin_bit_cast(half2v, __builtin_amdgcn_cvt_pkrtz(a, b));
}

// LUT silu in u-domain: input u = -log2e * x (from pre-scaled weights).
// sigma(x) = 1/(1+2^u) from table; returns p = u * sigma  (= c * silu(x)).
// Table: 1024 (base,delta) f32 pairs over u in [-24,24), du = 3/64.
__device__ __forceinline__ float lut_silu(const float2* __restrict__ LUT, float u) {
  float fu = fmaf(u, 64.0f / 3.0f, 512.0f);
  fu = fminf(fmaxf(fu, 0.0f), 1023.0f);    // v_med3
  const int i = (int)fu;
  const float f = fu - (float)i;
  const float2 e = LUT[i];                 // ds_read_b64
  return u * fmaf(f, e.y, e.x);
}

union H8 { half8 v8; half2v v2[4]; };
union H4 { half4v v4; half2v v2[2]; };

template <int CTRL>
__device__ __forceinline__ float dpp_radd(float x) {
  int yi = __builtin_amdgcn_update_dpp(0, __builtin_bit_cast(int, x), CTRL, 0xF, 0xF, false);
  return x + __builtin_bit_cast(float, yi);
}
__device__ __forceinline__ float row_sum16(float x) {
  x = dpp_radd<0xB1>(x);    // quad_perm [1,0,3,2]
  x = dpp_radd<0x4E>(x);    // quad_perm [2,3,0,1]
  x = dpp_radd<0x141>(x);   // row_half_mirror
  x = dpp_radd<0x140>(x);   // row_mirror
  return x;
}

__global__ __launch_bounds__(256) void mlp_kernel(
    const int* __restrict__ tix, const float* __restrict__ rho,
    const float* __restrict__ emb, const float* __restrict__ W0,
    const float* __restrict__ b0, const float* __restrict__ W1,
    const float* __restrict__ b1, const float* __restrict__ Wout,
    const float* __restrict__ bout, float* __restrict__ out, int ngroups)
{
  // Weights: fragment-order swizzle [s][t][lane][8 f16] -> 8 KB per layer.
  __shared__ __align__(16) _Float16 Wlds0[2][4][64][8];
  __shared__ __align__(16) _Float16 Wlds1[2][4][64][8];
  // H: per-wave single buffer, stride 72 halfs (144 B).
  __shared__ __align__(16) _Float16 ldsH[4][16][72];
  // sigma LUT: 1024 (base, delta) pairs, 8 KB.
  __shared__ __align__(8) float2 LUT[1024];

  const int tid  = threadIdx.x;
  const int wid  = tid >> 6;
  const int lane = tid & 63;
  const int m    = lane & 15;
  const int q    = lane >> 4;

  _Float16 (*Hb)[72] = ldsH[wid];

  // ---- init: sigma LUT (all threads, 4 entries each) ----
#pragma unroll
  for (int e = 0; e < 4; ++e) {
    const int idx = tid + 256 * e;
    const float u0 = (float)(idx - 512) * (3.0f / 64.0f);
    const float u1 = (float)(idx - 511) * (3.0f / 64.0f);
    const float s0 = fast_rcp(1.0f + fast_exp2(u0));
    const float s1 = fast_rcp(1.0f + fast_exp2(u1));
    LUT[idx] = make_float2(s0, s1 - s0);
  }

  // ---- init: wave 0 builds the swizzled weight fragments ----
  // content B[k=s*32+q*8+j][n=t*16+m]; A-op for L0 (=> W^T), B-op for L1.
  // L0 feature rows PERMUTED: k-window 32..63 = [cos1..8|sin1..8|rho,b0(1.0),0pad]
  // L0 fragments PRE-SCALED by c=-log2e (so MFMA emits u directly).
  if (wid == 0) {
#pragma unroll
    for (int t = 0; t < 4; ++t) {
#pragma unroll
      for (int s = 0; s < 2; ++s) {
        half8 f0, f1;
#pragma unroll
        for (int j = 0; j < 8; ++j) {
          const int k = s * 32 + q * 8 + j;
          const int n = t * 16 + m;
          float v0;
          if (k < 32) {
            v0 = W0[k * 64 + n];
          } else {
            const int kn = k - 32;
            v0 = (kn < 16) ? W0[(33 + kn) * 64 + n]
               : (kn == 16) ? W0[32 * 64 + n]
               : (kn == 17) ? b0[n] : 0.0f;
          }
          f0[j] = (_Float16)(CSCL * v0);
          f1[j] = (_Float16)W1[k * 64 + n];   // W1 UNSCALED (c cancels via p)
        }
        *(half8*)&Wlds0[s][t][lane][0] = f0;
        *(half8*)&Wlds1[s][t][lane][0] = f1;
      }
    }
  }

  float b1n[4], woutm[4];
#pragma unroll
  for (int t = 0; t < 4; ++t) {
    b1n[t]   = CSCL * b1[t * 16 + m];        // bias in u-domain
    woutm[t] = NLN2 * Wout[t * 16 + m];      // Wout/c: p2 -> true raw
  }
  const float boutBL = bout[0] + BASE_LOGIT;

  __syncthreads();   // weights + LUT visible (only barrier in kernel)

  const f32x4 z = {0.0f, 0.0f, 0.0f, 0.0f};
  const int gstride = gridDim.x * 4;

  int g = blockIdx.x * 4 + wid;
  if (g >= ngroups) return;          // after the barrier: safe

  int   tiL = tix[g * 64 + lane];
  float rh  = rho[g * 64 + lane];

  for (; g < ngroups; g += gstride) {
    const int gbase = g * 64;

    // prefetch next group's point data
    const int gn = (g + gstride < ngroups) ? (g + gstride) : g;
    const int   tiLn = tix[gn * 64 + lane];
    const float rhn  = rho[gn * 64 + lane];

    float dcar = 0.0f;  // raw output dot (true scale) for point gbase+lane

#pragma unroll
    for (int st = 0; st < 4; ++st) {
      // ---- emb gather in fragment layout ----
      const int tim  = __shfl(tiL, st * 16 + m, 64);
      const int idxm = min(max(tim - 1, 0), 510);
      const float* erow = emb + (size_t)idxm * 32 + q * 8;
      const f32x4 e0 = *(const f32x4*)erow;
      const f32x4 e1 = *(const f32x4*)(erow + 4);

      // ---- feature fragment, generated in-layout (one Chebyshev chain) ----
      const float rhp = __shfl(rh, st * 16 + m, 64);
      const float rev = 0.5f * rhp;  // v_sin/v_cos take revolutions
      const float c1  = __builtin_amdgcn_cosf(rev);
      const float s1f = __builtin_amdgcn_sinf(rev);
      const float tc  = 2.0f * c1;
      const float x1v = (q == 0) ? c1 : s1f;
      const float x0v = (q == 0) ? 1.0f : 0.0f;
      const float x2v = tc * x1v - x0v;
      const float x3v = tc * x2v - x1v;
      const float x4v = tc * x3v - x2v;
      const float x5v = tc * x4v - x3v;
      const float x6v = tc * x5v - x4v;
      const float x7v = tc * x6v - x5v;
      const float x8v = tc * x7v - x6v;
      H8 X1;
      X1.v2[0] = pkh(x1v, x2v);
      X1.v2[1] = pkh(x3v, x4v);
      X1.v2[2] = pkh(x5v, x6v);
      X1.v2[3] = pkh(x7v, x8v);
      {
        const half2v z2 = {};
        const half2v pr = pkh(rhp, 1.0f);
        const bool hi = (q >= 2);
        X1.v2[0] = hi ? ((q == 2) ? pr : z2) : X1.v2[0];
        X1.v2[1] = hi ? z2 : X1.v2[1];
        X1.v2[2] = hi ? z2 : X1.v2[2];
        X1.v2[3] = hi ? z2 : X1.v2[3];
      }
      H8 X0;
      X0.v2[0] = pkh(e0[0], e0[1]); X0.v2[1] = pkh(e0[2], e0[3]);
      X0.v2[2] = pkh(e1[0], e1[1]); X0.v2[3] = pkh(e1[2], e1[3]);

      // ---- L0 (transposed): acc = u = c * preact0, weights from LDS ----
      f32x4 acc[4];
#pragma unroll
      for (int t = 0; t < 4; ++t) {
        const half8 wA = *(const half8*)&Wlds0[0][t][lane][0];
        const half8 wB = *(const half8*)&Wlds0[1][t][lane][0];
        f32x4 a = __builtin_amdgcn_mfma_f32_16x16x32_f16(wA, X0.v8, z, 0, 0, 0);
        a = __builtin_amdgcn_mfma_f32_16x16x32_f16(wB, X1.v8, a, 0, 0, 0);
        acc[t] = a;
      }
      // epilogue: p = u*sigma (c*h1) via LUT -> packed f16 -> H
#pragma unroll
      for (int t = 0; t < 4; ++t) {
        H4 hh;
        hh.v2[0] = pkh(lut_silu(LUT, acc[t][0]), lut_silu(LUT, acc[t][1]));
        hh.v2[1] = pkh(lut_silu(LUT, acc[t][2]), lut_silu(LUT, acc[t][3]));
        *(half4v*)&Hb[m][t * 16 + q * 4] = hh.v4;
      }

      // ---- L1 (untransposed): acc = W1^T p + c*b1 = u1, weights from LDS ----
      const half8 Y0 = *(const half8*)&Hb[m][q * 8];        // in-order DS: RAW safe
      const half8 Y1 = *(const half8*)&Hb[m][32 + q * 8];
#pragma unroll
      for (int t = 0; t < 4; ++t) {
        const half8 w1A = *(const half8*)&Wlds1[0][t][lane][0];
        const half8 w1B = *(const half8*)&Wlds1[1][t][lane][0];
        const f32x4 binit = {b1n[t], b1n[t], b1n[t], b1n[t]};
        f32x4 a = __builtin_amdgcn_mfma_f32_16x16x32_f16(Y0, w1A, binit, 0, 0, 0);
        a = __builtin_amdgcn_mfma_f32_16x16x32_f16(Y1, w1B, a, 0, 0, 0);
        acc[t] = a;
      }
      // C[point=q*4+r][hidden=t*16+m]: p2 = u1*sigma; dot with pre-scaled Wout
      float dot0 = 0.0f, dot1 = 0.0f, dot2 = 0.0f, dot3 = 0.0f;
#pragma unroll
      for (int t = 0; t < 4; ++t) {
        dot0 = fmaf(lut_silu(LUT, acc[t][0]), woutm[t], dot0);
        dot1 = fmaf(lut_silu(LUT, acc[t][1]), woutm[t], dot1);
        dot2 = fmaf(lut_silu(LUT, acc[t][2]), woutm[t], dot2);
        dot3 = fmaf(lut_silu(LUT, acc[t][3]), woutm[t], dot3);
      }
      dot0 = row_sum16(dot0);
      dot1 = row_sum16(dot1);
      dot2 = row_sum16(dot2);
      dot3 = row_sum16(dot3);
      // route: value for point st*16+m lives as dots[m&3] in row (m>>2)
      const float dsel = (m & 2) ? ((m & 1) ? dot3 : dot2) : ((m & 1) ? dot1 : dot0);
      const float dg = __shfl(dsel, (m >> 2) * 16 + (m & 3), 64);
      dcar = (q == st) ? dg : dcar;
    }

    // ---- epilogue: precise sigmoid (1/lane), coalesced 256B store ----
    const float theta = sigf(dcar + boutBL);
    out[gbase + lane] = (tiL == 0) ? IC_VAL : theta * CSANMAX;

    tiL = tiLn; rh = rhn;
  }
}

extern "C" void kernel_launch(void* const* d_in, const int* in_sizes, int n_in,
                              void* d_out, int out_size, void* d_ws, size_t ws_size,
                              hipStream_t stream) {
  const int*   tix  = (const int*)d_in[0];
  const float* rho  = (const float*)d_in[1];
  const float* emb  = (const float*)d_in[2];
  const float* W0   = (const float*)d_in[3];
  const float* b0   = (const float*)d_in[4];
  const float* W1   = (const float*)d_in[5];
  const float* b1   = (const float*)d_in[6];
  const float* Wout = (const float*)d_in[7];
  const float* bout = (const float*)d_in[8];
  float* outp = (float*)d_out;

  const int n       = in_sizes[0];   // 2,000,000 (divisible by 64)
  const int ngroups = n / 64;        // 31,250 groups of 64 points

  // 4-wave blocks; LDS ~33.8 KB -> 4 blocks/CU -> 16 waves/CU
  int grid = 1024;
  const int maxg = (ngroups + 3) / 4;
  if (grid > maxg) grid = maxg;
  mlp_kernel<<<dim3(grid), dim3(256), 0, stream>>>(
      tix, rho, emb, W0, b0, W1, b1, Wout, bout, outp, ngroups);
}

// Round 12
// 170.274 us; speedup vs baseline: 1.2006x; 1.2006x over previous
//
#include <hip/hip_runtime.h>
#include <stdint.h>

// Fused MLP decode, MFMA f16. Wave = 64 points (4 sub-tiles of 16), 4-wave wg.
// Weights in workgroup LDS (fragment-order, conflict-free b128). Feature
// fragments generated in MFMA A-layout via one Chebyshev chain.
// Scale-folding (u-domain silu, EXP-based — LUT version regressed, R11):
//   W0,b0 pre-scaled by c=-log2e  ->  L0 MFMA emits u = c*x directly
//   sigma = rcp(1 + 2^u);  p = u*sigma = c*silu(x)
//   L1 consumes p with UNSCALED W1 (c carries through); b1 scaled by c
//   Wout scaled by -ln2 (=1/c) -> true raw logits
// Single-buffer per-wave H; ZERO barriers in the loop (in-order DS pipe).
// NOTE: __launch_bounds__ has NO min-waves arg (",4" caused 64-VGPR spills).

typedef _Float16 half8  __attribute__((ext_vector_type(8)));
typedef _Float16 half4v __attribute__((ext_vector_type(4)));
typedef _Float16 half2v __attribute__((ext_vector_type(2)));
typedef float f32x4 __attribute__((ext_vector_type(4)));

#define LOG2E 1.44269504088896340736f
#define NLN2  -0.6931471805599453f         // -ln2 = 1/(-log2e)
#define CSCL  -1.44269504088896340736f     // c = -log2e
#define BASE_LOGIT -0.84729786038720367f   // log(0.3/0.7)
#define CSANMAX 28700.0f
#define IC_VAL 8610.0f                     // 0.3 * 28700

__device__ __forceinline__ float fast_exp2(float x) { return __builtin_amdgcn_exp2f(x); }
__device__ __forceinline__ float fast_rcp(float x)  { return __builtin_amdgcn_rcpf(x); }
__device__ __forceinline__ float sigf(float x)  { return fast_rcp(1.0f + fast_exp2(-LOG2E * x)); }
// u-domain pair silu: inputs u0,u1 (= c*x). outputs p = u*sigma = c*silu(x).
// One rcp serves both: r = rcp(d0*d1); p0 = u0*d1*r; p1 = u1*d0*r.
__device__ __forceinline__ void usilu2(float u0, float u1, float& p0, float& p1) {
  const float d0 = 1.0f + fast_exp2(u0);
  const float d1 = 1.0f + fast_exp2(u1);
  const float r  = fast_rcp(d0 * d1);
  p0 = u0 * d1 * r;
  p1 = u1 * d0 * r;
}
__device__ __forceinline__ half2v pkh(float a, float b) {
  return __builtin_bit_cast(half2v, __builtin_amdgcn_cvt_pkrtz(a, b));
}

union H8 { half8 v8; half2v v2[4]; };
union H4 { half4v v4; half2v v2[2]; };

template <int CTRL>
__device__ __forceinline__ float dpp_radd(float x) {
  int yi = __builtin_amdgcn_update_dpp(0, __builtin_bit_cast(int, x), CTRL, 0xF, 0xF, false);
  return x + __builtin_bit_cast(float, yi);
}
__device__ __forceinline__ float row_sum16(float x) {
  x = dpp_radd<0xB1>(x);    // quad_perm [1,0,3,2]
  x = dpp_radd<0x4E>(x);    // quad_perm [2,3,0,1]
  x = dpp_radd<0x141>(x);   // row_half_mirror
  x = dpp_radd<0x140>(x);   // row_mirror
  return x;
}

__global__ __launch_bounds__(256) void mlp_kernel(
    const int* __restrict__ tix, const float* __restrict__ rho,
    const float* __restrict__ emb, const float* __restrict__ W0,
    const float* __restrict__ b0, const float* __restrict__ W1,
    const float* __restrict__ b1, const float* __restrict__ Wout,
    const float* __restrict__ bout, float* __restrict__ out, int ngroups)
{
  // Weights: fragment-order swizzle [s][t][lane][8 f16] -> 8 KB per layer.
  __shared__ __align__(16) _Float16 Wlds0[2][4][64][8];
  __shared__ __align__(16) _Float16 Wlds1[2][4][64][8];
  // H: per-wave single buffer, stride 72 halfs (144 B).
  __shared__ __align__(16) _Float16 ldsH[4][16][72];

  const int tid  = threadIdx.x;
  const int wid  = tid >> 6;
  const int lane = tid & 63;
  const int m    = lane & 15;
  const int q    = lane >> 4;

  _Float16 (*Hb)[72] = ldsH[wid];

  // ---- init: wave 0 builds the swizzled weight fragments ----
  // content B[k=s*32+q*8+j][n=t*16+m]; A-op for L0 (=> W^T), B-op for L1.
  // L0 feature rows PERMUTED: k-window 32..63 = [cos1..8|sin1..8|rho,b0(1.0),0pad]
  // L0 fragments PRE-SCALED by c=-log2e.
  if (wid == 0) {
#pragma unroll
    for (int t = 0; t < 4; ++t) {
#pragma unroll
      for (int s = 0; s < 2; ++s) {
        half8 f0, f1;
#pragma unroll
        for (int j = 0; j < 8; ++j) {
          const int k = s * 32 + q * 8 + j;
          const int n = t * 16 + m;
          float v0;
          if (k < 32) {
            v0 = W0[k * 64 + n];
          } else {
            const int kn = k - 32;
            v0 = (kn < 16) ? W0[(33 + kn) * 64 + n]
               : (kn == 16) ? W0[32 * 64 + n]
               : (kn == 17) ? b0[n] : 0.0f;
          }
          f0[j] = (_Float16)(CSCL * v0);
          f1[j] = (_Float16)W1[k * 64 + n];   // W1 UNSCALED (c rides through p)
        }
        *(half8*)&Wlds0[s][t][lane][0] = f0;
        *(half8*)&Wlds1[s][t][lane][0] = f1;
      }
    }
  }

  float b1n[4], woutm[4];
#pragma unroll
  for (int t = 0; t < 4; ++t) {
    b1n[t]   = CSCL * b1[t * 16 + m];        // bias in u-domain
    woutm[t] = NLN2 * Wout[t * 16 + m];      // p2 -> true raw
  }
  const float boutBL = bout[0] + BASE_LOGIT;

  __syncthreads();   // weights visible (only barrier in kernel)

  const f32x4 z = {0.0f, 0.0f, 0.0f, 0.0f};
  const int gstride = gridDim.x * 4;

  int g = blockIdx.x * 4 + wid;
  if (g >= ngroups) return;          // after the barrier: safe

  int   tiL = tix[g * 64 + lane];
  float rh  = rho[g * 64 + lane];

  for (; g < ngroups; g += gstride) {
    const int gbase = g * 64;

    // prefetch next group's point data
    const int gn = (g + gstride < ngroups) ? (g + gstride) : g;
    const int   tiLn = tix[gn * 64 + lane];
    const float rhn  = rho[gn * 64 + lane];

    float dcar = 0.0f;  // raw output dot (true scale) for point gbase+lane

#pragma unroll
    for (int st = 0; st < 4; ++st) {
      // ---- emb gather in fragment layout ----
      const int tim  = __shfl(tiL, st * 16 + m, 64);
      const int idxm = min(max(tim - 1, 0), 510);
      const float* erow = emb + (size_t)idxm * 32 + q * 8;
      const f32x4 e0 = *(const f32x4*)erow;
      const f32x4 e1 = *(const f32x4*)(erow + 4);

      // ---- feature fragment, generated in-layout (one Chebyshev chain) ----
      const float rhp = __shfl(rh, st * 16 + m, 64);
      const float rev = 0.5f * rhp;  // v_sin/v_cos take revolutions
      const float c1  = __builtin_amdgcn_cosf(rev);
      const float s1f = __builtin_amdgcn_sinf(rev);
      const float tc  = 2.0f * c1;
      const float x1v = (q == 0) ? c1 : s1f;
      const float x0v = (q == 0) ? 1.0f : 0.0f;
      const float x2v = tc * x1v - x0v;
      const float x3v = tc * x2v - x1v;
      const float x4v = tc * x3v - x2v;
      const float x5v = tc * x4v - x3v;
      const float x6v = tc * x5v - x4v;
      const float x7v = tc * x6v - x5v;
      const float x8v = tc * x7v - x6v;
      H8 X1;
      X1.v2[0] = pkh(x1v, x2v);
      X1.v2[1] = pkh(x3v, x4v);
      X1.v2[2] = pkh(x5v, x6v);
      X1.v2[3] = pkh(x7v, x8v);
      {
        const half2v z2 = {};
        const half2v pr = pkh(rhp, 1.0f);
        const bool hi = (q >= 2);
        X1.v2[0] = hi ? ((q == 2) ? pr : z2) : X1.v2[0];
        X1.v2[1] = hi ? z2 : X1.v2[1];
        X1.v2[2] = hi ? z2 : X1.v2[2];
        X1.v2[3] = hi ? z2 : X1.v2[3];
      }
      H8 X0;
      X0.v2[0] = pkh(e0[0], e0[1]); X0.v2[1] = pkh(e0[2], e0[3]);
      X0.v2[2] = pkh(e1[0], e1[1]); X0.v2[3] = pkh(e1[2], e1[3]);

      // ---- L0 (transposed): acc = u = c * preact0, weights from LDS ----
      f32x4 acc[4];
#pragma unroll
      for (int t = 0; t < 4; ++t) {
        const half8 wA = *(const half8*)&Wlds0[0][t][lane][0];
        const half8 wB = *(const half8*)&Wlds0[1][t][lane][0];
        f32x4 a = __builtin_amdgcn_mfma_f32_16x16x32_f16(wA, X0.v8, z, 0, 0, 0);
        a = __builtin_amdgcn_mfma_f32_16x16x32_f16(wB, X1.v8, a, 0, 0, 0);
        acc[t] = a;
      }
      // epilogue: p = u*sigma (= c*silu) -> packed f16 -> H
#pragma unroll
      for (int t = 0; t < 4; ++t) {
        float p0, p1, p2, p3;
        usilu2(acc[t][0], acc[t][1], p0, p1);
        usilu2(acc[t][2], acc[t][3], p2, p3);
        H4 hh;
        hh.v2[0] = pkh(p0, p1);
        hh.v2[1] = pkh(p2, p3);
        *(half4v*)&Hb[m][t * 16 + q * 4] = hh.v4;
      }

      // ---- L1 (untransposed): acc = W1^T p + c*b1 = u1, weights from LDS ----
      const half8 Y0 = *(const half8*)&Hb[m][q * 8];        // in-order DS: RAW safe
      const half8 Y1 = *(const half8*)&Hb[m][32 + q * 8];
#pragma unroll
      for (int t = 0; t < 4; ++t) {
        const half8 w1A = *(const half8*)&Wlds1[0][t][lane][0];
        const half8 w1B = *(const half8*)&Wlds1[1][t][lane][0];
        const f32x4 binit = {b1n[t], b1n[t], b1n[t], b1n[t]};
        f32x4 a = __builtin_amdgcn_mfma_f32_16x16x32_f16(Y0, w1A, binit, 0, 0, 0);
        a = __builtin_amdgcn_mfma_f32_16x16x32_f16(Y1, w1B, a, 0, 0, 0);
        acc[t] = a;
      }
      // C[point=q*4+r][hidden=t*16+m]: p2 = u1*sigma; dot with pre-scaled Wout
      float dot0 = 0.0f, dot1 = 0.0f, dot2 = 0.0f, dot3 = 0.0f;
#pragma unroll
      for (int t = 0; t < 4; ++t) {
        float p0, p1, p2, p3;
        usilu2(acc[t][0], acc[t][1], p0, p1);
        usilu2(acc[t][2], acc[t][3], p2, p3);
        dot0 = fmaf(p0, woutm[t], dot0);
        dot1 = fmaf(p1, woutm[t], dot1);
        dot2 = fmaf(p2, woutm[t], dot2);
        dot3 = fmaf(p3, woutm[t], dot3);
      }
      dot0 = row_sum16(dot0);
      dot1 = row_sum16(dot1);
      dot2 = row_sum16(dot2);
      dot3 = row_sum16(dot3);
      // route: value for point st*16+m lives as dots[m&3] in row (m>>2)
      const float dsel = (m & 2) ? ((m & 1) ? dot3 : dot2) : ((m & 1) ? dot1 : dot0);
      const float dg = __shfl(dsel, (m >> 2) * 16 + (m & 3), 64);
      dcar = (q == st) ? dg : dcar;
    }

    // ---- epilogue: precise sigmoid (1/lane), coalesced 256B store ----
    const float theta = sigf(dcar + boutBL);
    out[gbase + lane] = (tiL == 0) ? IC_VAL : theta * CSANMAX;

    tiL = tiLn; rh = rhn;
  }
}

extern "C" void kernel_launch(void* const* d_in, const int* in_sizes, int n_in,
                              void* d_out, int out_size, void* d_ws, size_t ws_size,
                              hipStream_t stream) {
  const int*   tix  = (const int*)d_in[0];
  const float* rho  = (const float*)d_in[1];
  const float* emb  = (const float*)d_in[2];
  const float* W0   = (const float*)d_in[3];
  const float* b0   = (const float*)d_in[4];
  const float* W1   = (const float*)d_in[5];
  const float* b1   = (const float*)d_in[6];
  const float* Wout = (const float*)d_in[7];
  const float* bout = (const float*)d_in[8];
  float* outp = (float*)d_out;

  const int n       = in_sizes[0];   // 2,000,000 (divisible by 64)
  const int ngroups = n / 64;        // 31,250 groups of 64 points

  // 4-wave blocks; LDS 25600 B -> 6 blocks/CU
  int grid = 1536;
  const int maxg = (ngroups + 3) / 4;
  if (grid > maxg) grid = maxg;
  mlp_kernel<<<dim3(grid), dim3(256), 0, stream>>>(
      tix, rho, emb, W0, b0, W1, b1, Wout, bout, outp, ngroups);
}

// Round 13
// 169.907 us; speedup vs baseline: 1.2032x; 1.0022x over previous
//
#include <hip/hip_runtime.h>
#include <stdint.h>

// Fused MLP decode, MFMA f16. Wave = 64 points (4 sub-tiles of 16), 4-wave wg.
// Weights in workgroup LDS (fragment-order, conflict-free b128). Feature
// fragments generated in MFMA A-layout via one Chebyshev chain.
// Scale-folding (u-domain silu, EXP-based):
//   W0,b0 pre-scaled by c=-log2e  ->  L0 MFMA emits u = c*x directly
//   sigma = rcp(1 + 2^u);  p = u*sigma = c*silu(x)
//   L1 consumes p with UNSCALED W1; b1 scaled by c; Wout scaled by -ln2.
// R13 micro-pass: hoisted persistent b1 C-operands (MFMA D!=C, no per-iter
// movs), all 4 sub-tile tim/rho shuffles hoisted to group top (removes DS
// latency from each sub-tile's serial chain), group-prefetch regs dropped.
// Single-buffer per-wave H; ZERO barriers in the loop (in-order DS pipe).
// NOTE: __launch_bounds__ has NO min-waves arg (",4" caused 64-VGPR spills).

typedef _Float16 half8  __attribute__((ext_vector_type(8)));
typedef _Float16 half4v __attribute__((ext_vector_type(4)));
typedef _Float16 half2v __attribute__((ext_vector_type(2)));
typedef float f32x4 __attribute__((ext_vector_type(4)));

#define LOG2E 1.44269504088896340736f
#define NLN2  -0.6931471805599453f         // -ln2 = 1/(-log2e)
#define CSCL  -1.44269504088896340736f     // c = -log2e
#define BASE_LOGIT -0.84729786038720367f   // log(0.3/0.7)
#define CSANMAX 28700.0f
#define IC_VAL 8610.0f                     // 0.3 * 28700

__device__ __forceinline__ float fast_exp2(float x) { return __builtin_amdgcn_exp2f(x); }
__device__ __forceinline__ float fast_rcp(float x)  { return __builtin_amdgcn_rcpf(x); }
__device__ __forceinline__ float sigf(float x)  { return fast_rcp(1.0f + fast_exp2(-LOG2E * x)); }
// u-domain pair silu: inputs u0,u1 (= c*x). outputs p = u*sigma = c*silu(x).
__device__ __forceinline__ void usilu2(float u0, float u1, float& p0, float& p1) {
  const float d0 = 1.0f + fast_exp2(u0);
  const float d1 = 1.0f + fast_exp2(u1);
  const float r  = fast_rcp(d0 * d1);
  p0 = u0 * d1 * r;
  p1 = u1 * d0 * r;
}
__device__ __forceinline__ half2v pkh(float a, float b) {
  return __builtin_bit_cast(half2v, __builtin_amdgcn_cvt_pkrtz(a, b));
}

union H8 { half8 v8; half2v v2[4]; };
union H4 { half4v v4; half2v v2[2]; };

template <int CTRL>
__device__ __forceinline__ float dpp_radd(float x) {
  int yi = __builtin_amdgcn_update_dpp(0, __builtin_bit_cast(int, x), CTRL, 0xF, 0xF, false);
  return x + __builtin_bit_cast(float, yi);
}
__device__ __forceinline__ float row_sum16(float x) {
  x = dpp_radd<0xB1>(x);    // quad_perm [1,0,3,2]
  x = dpp_radd<0x4E>(x);    // quad_perm [2,3,0,1]
  x = dpp_radd<0x141>(x);   // row_half_mirror
  x = dpp_radd<0x140>(x);   // row_mirror
  return x;
}

__global__ __launch_bounds__(256) void mlp_kernel(
    const int* __restrict__ tix, const float* __restrict__ rho,
    const float* __restrict__ emb, const float* __restrict__ W0,
    const float* __restrict__ b0, const float* __restrict__ W1,
    const float* __restrict__ b1, const float* __restrict__ Wout,
    const float* __restrict__ bout, float* __restrict__ out, int ngroups)
{
  // Weights: fragment-order swizzle [s][t][lane][8 f16] -> 8 KB per layer.
  __shared__ __align__(16) _Float16 Wlds0[2][4][64][8];
  __shared__ __align__(16) _Float16 Wlds1[2][4][64][8];
  // H: per-wave single buffer, stride 72 halfs (144 B) -> 2-way banks (free).
  __shared__ __align__(16) _Float16 ldsH[4][16][72];

  const int tid  = threadIdx.x;
  const int wid  = tid >> 6;
  const int lane = tid & 63;
  const int m    = lane & 15;
  const int q    = lane >> 4;

  _Float16 (*Hb)[72] = ldsH[wid];

  // ---- init: wave 0 builds the swizzled weight fragments ----
  // content B[k=s*32+q*8+j][n=t*16+m]; A-op for L0 (=> W^T), B-op for L1.
  // L0 feature rows PERMUTED: k-window 32..63 = [cos1..8|sin1..8|rho,b0(1.0),0pad]
  // L0 fragments PRE-SCALED by c=-log2e.
  if (wid == 0) {
#pragma unroll
    for (int t = 0; t < 4; ++t) {
#pragma unroll
      for (int s = 0; s < 2; ++s) {
        half8 f0, f1;
#pragma unroll
        for (int j = 0; j < 8; ++j) {
          const int k = s * 32 + q * 8 + j;
          const int n = t * 16 + m;
          float v0;
          if (k < 32) {
            v0 = W0[k * 64 + n];
          } else {
            const int kn = k - 32;
            v0 = (kn < 16) ? W0[(33 + kn) * 64 + n]
               : (kn == 16) ? W0[32 * 64 + n]
               : (kn == 17) ? b0[n] : 0.0f;
          }
          f0[j] = (_Float16)(CSCL * v0);
          f1[j] = (_Float16)W1[k * 64 + n];   // W1 UNSCALED (c rides through p)
        }
        *(half8*)&Wlds0[s][t][lane][0] = f0;
        *(half8*)&Wlds1[s][t][lane][0] = f1;
      }
    }
  }

  // persistent L1 C-operands (u-domain bias) — MFMA D and C are separate
  // register fields, so these are read every sub-tile with NO per-iter movs.
  f32x4 b1acc[4];
  float woutm[4];
#pragma unroll
  for (int t = 0; t < 4; ++t) {
    const float bv = CSCL * b1[t * 16 + m];
    b1acc[t] = (f32x4){bv, bv, bv, bv};
    woutm[t] = NLN2 * Wout[t * 16 + m];      // p2 -> true raw
  }
  const float boutBL = bout[0] + BASE_LOGIT;

  __syncthreads();   // weights visible (only barrier in kernel)

  const f32x4 z = {0.0f, 0.0f, 0.0f, 0.0f};
  const int gstride = gridDim.x * 4;

  int g = blockIdx.x * 4 + wid;
  if (g >= ngroups) return;          // after the barrier: safe

  for (; g < ngroups; g += gstride) {
    const int gbase = g * 64;

    // ---- group head: coalesced point loads ----
    const int   tiL = tix[gbase + lane];
    const float rh  = rho[gbase + lane];

    // hoisted: all 4 sub-tiles' shuffles (removes DS latency from each
    // sub-tile's serial chain) + gather base pointers
    int   tim4[4];
    float rhp4[4];
#pragma unroll
    for (int st = 0; st < 4; ++st) {
      tim4[st] = __shfl(tiL, st * 16 + m, 64);
      rhp4[st] = __shfl(rh,  st * 16 + m, 64);
    }

    float dcar = 0.0f;  // raw output dot (true scale) for point gbase+lane

#pragma unroll
    for (int st = 0; st < 4; ++st) {
      // ---- emb gather in fragment layout ----
      const int idxm = min(max(tim4[st] - 1, 0), 510);
      const float* erow = emb + (size_t)idxm * 32 + q * 8;
      const f32x4 e0 = *(const f32x4*)erow;
      const f32x4 e1 = *(const f32x4*)(erow + 4);

      // ---- feature fragment, generated in-layout (one Chebyshev chain) ----
      const float rhp = rhp4[st];
      const float rev = 0.5f * rhp;  // v_sin/v_cos take revolutions
      const float c1  = __builtin_amdgcn_cosf(rev);
      const float s1f = __builtin_amdgcn_sinf(rev);
      const float tc  = 2.0f * c1;
      const float x1v = (q == 0) ? c1 : s1f;
      const float x0v = (q == 0) ? 1.0f : 0.0f;
      const float x2v = tc * x1v - x0v;
      const float x3v = tc * x2v - x1v;
      const float x4v = tc * x3v - x2v;
      const float x5v = tc * x4v - x3v;
      const float x6v = tc * x5v - x4v;
      const float x7v = tc * x6v - x5v;
      const float x8v = tc * x7v - x6v;
      H8 X1;
      X1.v2[0] = pkh(x1v, x2v);
      X1.v2[1] = pkh(x3v, x4v);
      X1.v2[2] = pkh(x5v, x6v);
      X1.v2[3] = pkh(x7v, x8v);
      {
        const half2v z2 = {};
        const half2v pr = pkh(rhp, 1.0f);
        const bool hi = (q >= 2);
        X1.v2[0] = hi ? ((q == 2) ? pr : z2) : X1.v2[0];
        X1.v2[1] = hi ? z2 : X1.v2[1];
        X1.v2[2] = hi ? z2 : X1.v2[2];
        X1.v2[3] = hi ? z2 : X1.v2[3];
      }
      H8 X0;
      X0.v2[0] = pkh(e0[0], e0[1]); X0.v2[1] = pkh(e0[2], e0[3]);
      X0.v2[2] = pkh(e1[0], e1[1]); X0.v2[3] = pkh(e1[2], e1[3]);

      // ---- L0 (transposed): acc = u = c * preact0, weights from LDS ----
      f32x4 acc[4];
#pragma unroll
      for (int t = 0; t < 4; ++t) {
        const half8 wA = *(const half8*)&Wlds0[0][t][lane][0];
        const half8 wB = *(const half8*)&Wlds0[1][t][lane][0];
        f32x4 a = __builtin_amdgcn_mfma_f32_16x16x32_f16(wA, X0.v8, z, 0, 0, 0);
        a = __builtin_amdgcn_mfma_f32_16x16x32_f16(wB, X1.v8, a, 0, 0, 0);
        acc[t] = a;
      }
      // epilogue: p = u*sigma (= c*silu) -> packed f16 -> H
#pragma unroll
      for (int t = 0; t < 4; ++t) {
        float p0, p1, p2, p3;
        usilu2(acc[t][0], acc[t][1], p0, p1);
        usilu2(acc[t][2], acc[t][3], p2, p3);
        H4 hh;
        hh.v2[0] = pkh(p0, p1);
        hh.v2[1] = pkh(p2, p3);
        *(half4v*)&Hb[m][t * 16 + q * 4] = hh.v4;
      }

      // ---- L1 (untransposed): acc = W1^T p + c*b1, C = persistent b1acc ----
      const half8 Y0 = *(const half8*)&Hb[m][q * 8];        // in-order DS: RAW safe
      const half8 Y1 = *(const half8*)&Hb[m][32 + q * 8];
#pragma unroll
      for (int t = 0; t < 4; ++t) {
        const half8 w1A = *(const half8*)&Wlds1[0][t][lane][0];
        const half8 w1B = *(const half8*)&Wlds1[1][t][lane][0];
        f32x4 a = __builtin_amdgcn_mfma_f32_16x16x32_f16(Y0, w1A, b1acc[t], 0, 0, 0);
        a = __builtin_amdgcn_mfma_f32_16x16x32_f16(Y1, w1B, a, 0, 0, 0);
        acc[t] = a;
      }
      // C[point=q*4+r][hidden=t*16+m]: p2 = u1*sigma; dot with pre-scaled Wout
      float dot0 = 0.0f, dot1 = 0.0f, dot2 = 0.0f, dot3 = 0.0f;
#pragma unroll
      for (int t = 0; t < 4; ++t) {
        float p0, p1, p2, p3;
        usilu2(acc[t][0], acc[t][1], p0, p1);
        usilu2(acc[t][2], acc[t][3], p2, p3);
        dot0 = fmaf(p0, woutm[t], dot0);
        dot1 = fmaf(p1, woutm[t], dot1);
        dot2 = fmaf(p2, woutm[t], dot2);
        dot3 = fmaf(p3, woutm[t], dot3);
      }
      dot0 = row_sum16(dot0);
      dot1 = row_sum16(dot1);
      dot2 = row_sum16(dot2);
      dot3 = row_sum16(dot3);
      // route: value for point st*16+m lives as dots[m&3] in row (m>>2)
      const float dsel = (m & 2) ? ((m & 1) ? dot3 : dot2) : ((m & 1) ? dot1 : dot0);
      const float dg = __shfl(dsel, (m >> 2) * 16 + (m & 3), 64);
      dcar = (q == st) ? dg : dcar;
    }

    // ---- epilogue: precise sigmoid (1/lane), coalesced 256B store ----
    const float theta = sigf(dcar + boutBL);
    out[gbase + lane] = (tiL == 0) ? IC_VAL : theta * CSANMAX;
  }
}

extern "C" void kernel_launch(void* const* d_in, const int* in_sizes, int n_in,
                              void* d_out, int out_size, void* d_ws, size_t ws_size,
                              hipStream_t stream) {
  const int*   tix  = (const int*)d_in[0];
  const float* rho  = (const float*)d_in[1];
  const float* emb  = (const float*)d_in[2];
  const float* W0   = (const float*)d_in[3];
  const float* b0   = (const float*)d_in[4];
  const float* W1   = (const float*)d_in[5];
  const float* b1   = (const float*)d_in[6];
  const float* Wout = (const float*)d_in[7];
  const float* bout = (const float*)d_in[8];
  float* outp = (float*)d_out;

  const int n       = in_sizes[0];   // 2,000,000 (divisible by 64)
  const int ngroups = n / 64;        // 31,250 groups of 64 points

  // 4-wave blocks; LDS 25600 B -> 6 blocks/CU
  int grid = 1536;
  const int maxg = (ngroups + 3) / 4;
  if (grid > maxg) grid = maxg;
  mlp_kernel<<<dim3(grid), dim3(256), 0, stream>>>(
      tix, rho, emb, W0, b0, W1, b1, Wout, bout, outp, ngroups);
}

// Round 14
// 168.338 us; speedup vs baseline: 1.2144x; 1.0093x over previous
//
#include <hip/hip_runtime.h>
#include <stdint.h>

// Fused MLP decode, MFMA f16. Wave = 64 points (4 sub-tiles of 16), 4-wave wg.
// Weights in workgroup LDS (fragment-order, conflict-free b128). Feature
// fragments generated in MFMA A-layout via one Chebyshev chain (chain seeded
// to 0 for q>=2 lanes -> zero-pad falls out of the recurrence, no selects).
// Scale-folding (u-domain silu, EXP-based):
//   W0,b0 pre-scaled by c=-log2e  ->  L0 MFMA emits u = c*x directly
//   sigma = rcp(1 + 2^u);  p = u*sigma = c*silu(x)
//   L1 consumes p with UNSCALED W1; b1 scaled by c (persistent C-operand);
//   Wout scaled by -ln2 -> true raw logits.
// L0 weight ds_reads hoisted above feature-gen (lgkm drains under VALU).
// Single-buffer per-wave H; ZERO barriers in the loop (in-order DS pipe).
// NOTE: __launch_bounds__ has NO min-waves arg (",4" caused 64-VGPR spills).

typedef _Float16 half8  __attribute__((ext_vector_type(8)));
typedef _Float16 half4v __attribute__((ext_vector_type(4)));
typedef _Float16 half2v __attribute__((ext_vector_type(2)));
typedef float f32x4 __attribute__((ext_vector_type(4)));

#define LOG2E 1.44269504088896340736f
#define NLN2  -0.6931471805599453f         // -ln2 = 1/(-log2e)
#define CSCL  -1.44269504088896340736f     // c = -log2e
#define BASE_LOGIT -0.84729786038720367f   // log(0.3/0.7)
#define CSANMAX 28700.0f
#define IC_VAL 8610.0f                     // 0.3 * 28700

__device__ __forceinline__ float fast_exp2(float x) { return __builtin_amdgcn_exp2f(x); }
__device__ __forceinline__ float fast_rcp(float x)  { return __builtin_amdgcn_rcpf(x); }
__device__ __forceinline__ float sigf(float x)  { return fast_rcp(1.0f + fast_exp2(-LOG2E * x)); }
// u-domain pair silu: inputs u0,u1 (= c*x). outputs p = u*sigma = c*silu(x).
__device__ __forceinline__ void usilu2(float u0, float u1, float& p0, float& p1) {
  const float d0 = 1.0f + fast_exp2(u0);
  const float d1 = 1.0f + fast_exp2(u1);
  const float r  = fast_rcp(d0 * d1);
  p0 = u0 * d1 * r;
  p1 = u1 * d0 * r;
}
__device__ __forceinline__ half2v pkh(float a, float b) {
  return __builtin_bit_cast(half2v, __builtin_amdgcn_cvt_pkrtz(a, b));
}

union H8 { half8 v8; half2v v2[4]; };
union H4 { half4v v4; half2v v2[2]; };

template <int CTRL>
__device__ __forceinline__ float dpp_radd(float x) {
  int yi = __builtin_amdgcn_update_dpp(0, __builtin_bit_cast(int, x), CTRL, 0xF, 0xF, false);
  return x + __builtin_bit_cast(float, yi);
}
__device__ __forceinline__ float row_sum16(float x) {
  x = dpp_radd<0xB1>(x);    // quad_perm [1,0,3,2]
  x = dpp_radd<0x4E>(x);    // quad_perm [2,3,0,1]
  x = dpp_radd<0x141>(x);   // row_half_mirror
  x = dpp_radd<0x140>(x);   // row_mirror
  return x;
}

__global__ __launch_bounds__(256) void mlp_kernel(
    const int* __restrict__ tix, const float* __restrict__ rho,
    const float* __restrict__ emb, const float* __restrict__ W0,
    const float* __restrict__ b0, const float* __restrict__ W1,
    const float* __restrict__ b1, const float* __restrict__ Wout,
    const float* __restrict__ bout, float* __restrict__ out, int ngroups)
{
  // Weights: fragment-order swizzle [s][t][lane][8 f16] -> 8 KB per layer.
  __shared__ __align__(16) _Float16 Wlds0[2][4][64][8];
  __shared__ __align__(16) _Float16 Wlds1[2][4][64][8];
  // H: per-wave single buffer, stride 72 halfs (144 B) -> 2-way banks (free).
  __shared__ __align__(16) _Float16 ldsH[4][16][72];

  const int tid  = threadIdx.x;
  const int wid  = tid >> 6;
  const int lane = tid & 63;
  const int m    = lane & 15;
  const int q    = lane >> 4;

  _Float16 (*Hb)[72] = ldsH[wid];

  // ---- init: wave 0 builds the swizzled weight fragments ----
  // content B[k=s*32+q*8+j][n=t*16+m]; A-op for L0 (=> W^T), B-op for L1.
  // L0 feature rows PERMUTED: k-window 32..63 = [cos1..8|sin1..8|rho,b0(1.0),0pad]
  // L0 fragments PRE-SCALED by c=-log2e.
  if (wid == 0) {
#pragma unroll
    for (int t = 0; t < 4; ++t) {
#pragma unroll
      for (int s = 0; s < 2; ++s) {
        half8 f0, f1;
#pragma unroll
        for (int j = 0; j < 8; ++j) {
          const int k = s * 32 + q * 8 + j;
          const int n = t * 16 + m;
          float v0;
          if (k < 32) {
            v0 = W0[k * 64 + n];
          } else {
            const int kn = k - 32;
            v0 = (kn < 16) ? W0[(33 + kn) * 64 + n]
               : (kn == 16) ? W0[32 * 64 + n]
               : (kn == 17) ? b0[n] : 0.0f;
          }
          f0[j] = (_Float16)(CSCL * v0);
          f1[j] = (_Float16)W1[k * 64 + n];   // W1 UNSCALED (c rides through p)
        }
        *(half8*)&Wlds0[s][t][lane][0] = f0;
        *(half8*)&Wlds1[s][t][lane][0] = f1;
      }
    }
  }

  // persistent L1 C-operands (u-domain bias) — read by MFMA with no movs.
  f32x4 b1acc[4];
  float woutm[4];
#pragma unroll
  for (int t = 0; t < 4; ++t) {
    const float bv = CSCL * b1[t * 16 + m];
    b1acc[t] = (f32x4){bv, bv, bv, bv};
    woutm[t] = NLN2 * Wout[t * 16 + m];      // p2 -> true raw
  }
  const float boutBL = bout[0] + BASE_LOGIT;

  __syncthreads();   // weights visible (only barrier in kernel)

  const f32x4 z = {0.0f, 0.0f, 0.0f, 0.0f};
  const int gstride = gridDim.x * 4;

  int g = blockIdx.x * 4 + wid;
  if (g >= ngroups) return;          // after the barrier: safe

  for (; g < ngroups; g += gstride) {
    const int gbase = g * 64;

    // ---- group head: coalesced point loads + hoisted shuffles ----
    const int   tiL = tix[gbase + lane];
    const float rh  = rho[gbase + lane];

    int   tim4[4];
    float rhp4[4];
#pragma unroll
    for (int st = 0; st < 4; ++st) {
      tim4[st] = __shfl(tiL, st * 16 + m, 64);
      rhp4[st] = __shfl(rh,  st * 16 + m, 64);
    }

    float dcar = 0.0f;  // raw output dot (true scale) for point gbase+lane

#pragma unroll
    for (int st = 0; st < 4; ++st) {
      // ---- hoisted: L0 weight fragments (lgkm drains under feature VALU) ----
      half8 w0A[4], w0B[4];
#pragma unroll
      for (int t = 0; t < 4; ++t) {
        w0A[t] = *(const half8*)&Wlds0[0][t][lane][0];
        w0B[t] = *(const half8*)&Wlds0[1][t][lane][0];
      }

      // ---- emb gather in fragment layout ----
      const int idxm = min(max(tim4[st] - 1, 0), 510);
      const float* erow = emb + (size_t)idxm * 32 + q * 8;
      const f32x4 e0 = *(const f32x4*)erow;
      const f32x4 e1 = *(const f32x4*)(erow + 4);

      // ---- feature fragment, in-layout Chebyshev chain ----
      // seed 0 for q>=2: the whole chain then emits the zero-pad for free.
      const float rhp = rhp4[st];
      const float rev = 0.5f * rhp;  // v_sin/v_cos take revolutions
      const float c1  = __builtin_amdgcn_cosf(rev);
      const float s1f = __builtin_amdgcn_sinf(rev);
      const float tc  = 2.0f * c1;
      const float x1v = (q == 0) ? c1 : ((q == 1) ? s1f : 0.0f);
      const float x0v = (q == 0) ? 1.0f : 0.0f;
      const float x2v = tc * x1v - x0v;
      const float x3v = tc * x2v - x1v;
      const float x4v = tc * x3v - x2v;
      const float x5v = tc * x4v - x3v;
      const float x6v = tc * x5v - x4v;
      const float x7v = tc * x6v - x5v;
      const float x8v = tc * x7v - x6v;
      H8 X1;
      X1.v2[0] = (q == 2) ? pkh(rhp, 1.0f) : pkh(x1v, x2v);  // q==2: (rho, b0-slot)
      X1.v2[1] = pkh(x3v, x4v);
      X1.v2[2] = pkh(x5v, x6v);
      X1.v2[3] = pkh(x7v, x8v);
      H8 X0;
      X0.v2[0] = pkh(e0[0], e0[1]); X0.v2[1] = pkh(e0[2], e0[3]);
      X0.v2[2] = pkh(e1[0], e1[1]); X0.v2[3] = pkh(e1[2], e1[3]);

      // ---- L0 (transposed): acc = u = c * preact0 ----
      f32x4 acc[4];
#pragma unroll
      for (int t = 0; t < 4; ++t) {
        f32x4 a = __builtin_amdgcn_mfma_f32_16x16x32_f16(w0A[t], X0.v8, z, 0, 0, 0);
        a = __builtin_amdgcn_mfma_f32_16x16x32_f16(w0B[t], X1.v8, a, 0, 0, 0);
        acc[t] = a;
      }
      // epilogue: p = u*sigma (= c*silu) -> packed f16 -> H
#pragma unroll
      for (int t = 0; t < 4; ++t) {
        float p0, p1, p2, p3;
        usilu2(acc[t][0], acc[t][1], p0, p1);
        usilu2(acc[t][2], acc[t][3], p2, p3);
        H4 hh;
        hh.v2[0] = pkh(p0, p1);
        hh.v2[1] = pkh(p2, p3);
        *(half4v*)&Hb[m][t * 16 + q * 4] = hh.v4;
      }

      // ---- L1 (untransposed): acc = W1^T p + c*b1, C = persistent b1acc ----
      const half8 Y0 = *(const half8*)&Hb[m][q * 8];        // in-order DS: RAW safe
      const half8 Y1 = *(const half8*)&Hb[m][32 + q * 8];
#pragma unroll
      for (int t = 0; t < 4; ++t) {
        const half8 w1A = *(const half8*)&Wlds1[0][t][lane][0];
        const half8 w1B = *(const half8*)&Wlds1[1][t][lane][0];
        f32x4 a = __builtin_amdgcn_mfma_f32_16x16x32_f16(Y0, w1A, b1acc[t], 0, 0, 0);
        a = __builtin_amdgcn_mfma_f32_16x16x32_f16(Y1, w1B, a, 0, 0, 0);
        acc[t] = a;
      }
      // C[point=q*4+r][hidden=t*16+m]: p2 = u1*sigma; dot with pre-scaled Wout
      float dot0 = 0.0f, dot1 = 0.0f, dot2 = 0.0f, dot3 = 0.0f;
#pragma unroll
      for (int t = 0; t < 4; ++t) {
        float p0, p1, p2, p3;
        usilu2(acc[t][0], acc[t][1], p0, p1);
        usilu2(acc[t][2], acc[t][3], p2, p3);
        dot0 = fmaf(p0, woutm[t], dot0);
        dot1 = fmaf(p1, woutm[t], dot1);
        dot2 = fmaf(p2, woutm[t], dot2);
        dot3 = fmaf(p3, woutm[t], dot3);
      }
      dot0 = row_sum16(dot0);
      dot1 = row_sum16(dot1);
      dot2 = row_sum16(dot2);
      dot3 = row_sum16(dot3);
      // route: value for point st*16+m lives as dots[m&3] in row (m>>2)
      const float dsel = (m & 2) ? ((m & 1) ? dot3 : dot2) : ((m & 1) ? dot1 : dot0);
      const float dg = __shfl(dsel, (m >> 2) * 16 + (m & 3), 64);
      dcar = (q == st) ? dg : dcar;
    }

    // ---- epilogue: precise sigmoid (1/lane), coalesced 256B store ----
    const float theta = sigf(dcar + boutBL);
    out[gbase + lane] = (tiL == 0) ? IC_VAL : theta * CSANMAX;
  }
}

extern "C" void kernel_launch(void* const* d_in, const int* in_sizes, int n_in,
                              void* d_out, int out_size, void* d_ws, size_t ws_size,
                              hipStream_t stream) {
  const int*   tix  = (const int*)d_in[0];
  const float* rho  = (const float*)d_in[1];
  const float* emb  = (const float*)d_in[2];
  const float* W0   = (const float*)d_in[3];
  const float* b0   = (const float*)d_in[4];
  const float* W1   = (const float*)d_in[5];
  const float* b1   = (const float*)d_in[6];
  const float* Wout = (const float*)d_in[7];
  const float* bout = (const float*)d_in[8];
  float* outp = (float*)d_out;

  const int n       = in_sizes[0];   // 2,000,000 (divisible by 64)
  const int ngroups = n / 64;        // 31,250 groups of 64 points

  // 4-wave blocks; LDS 25600 B -> 6 blocks/CU
  int grid = 1536;
  const int maxg = (ngroups + 3) / 4;
  if (grid > maxg) grid = maxg;
  mlp_kernel<<<dim3(grid), dim3(256), 0, stream>>>(
      tix, rho, emb, W0, b0, W1, b1, Wout, bout, outp, ngroups);
}